// Round 3
// baseline (66.719 us; speedup 1.0000x reference)
//
#include <hip/hip_runtime.h>

#define STEPV (1.0f / 7.0f)
#define L_COORD 5.0f
#define L_NOOBJ 0.5f
#define EPSV 1e-6f

#define TILE 256            // cells per block
#define FLOATS_PER_CELL 30
#define TILE_FLOATS (TILE * FLOATS_PER_CELL)   // 7680 floats = 30720 B
#define TILE_F4 (TILE_FLOATS / 4)              // 1920 float4 (NOT divisible by 256!)
#define STAGE_ITERS ((TILE_F4 + 255) / 256)    // 8

__global__ __launch_bounds__(256) void yolo_loss_kernel(
    const float* __restrict__ pred,
    const float* __restrict__ tgt,
    double* __restrict__ acc,
    int ncells)
{
    __shared__ float buf[TILE_FLOATS];

    const int tid = threadIdx.x;
    const int cell = blockIdx.x * TILE + tid;
    const int base_f4 = blockIdx.x * TILE_F4;

    // ---- Phase A: stage pred tile (coalesced float4), copy own cell to regs
    {
        const float4* src = reinterpret_cast<const float4*>(pred);
        float4* dst = reinterpret_cast<float4*>(buf);
        #pragma unroll
        for (int i = 0; i < STAGE_ITERS; ++i) {
            int li = tid + i * 256;
            if (li < TILE_F4) dst[li] = src[base_f4 + li];   // grid is exact: no global guard needed
        }
    }
    __syncthreads();

    float pv[FLOATS_PER_CELL];
    {
        const float* my = buf + tid * FLOATS_PER_CELL;
        #pragma unroll
        for (int k = 0; k < 15; ++k) {
            float2 a = *reinterpret_cast<const float2*>(my + 2 * k);
            pv[2 * k] = a.x; pv[2 * k + 1] = a.y;
        }
    }
    __syncthreads();   // everyone done reading pred before overwrite

    // ---- Phase B: stage target tile into the same buffer
    {
        const float4* src = reinterpret_cast<const float4*>(tgt);
        float4* dst = reinterpret_cast<float4*>(buf);
        #pragma unroll
        for (int i = 0; i < STAGE_ITERS; ++i) {
            int li = tid + i * 256;
            if (li < TILE_F4) dst[li] = src[base_f4 + li];
        }
    }
    __syncthreads();

    float loss = 0.0f;
    if (cell < ncells) {
        float tv[FLOATS_PER_CELL];
        {
            const float* my = buf + tid * FLOATS_PER_CELL;
            #pragma unroll
            for (int k = 0; k < 15; ++k) {
                float2 a = *reinterpret_cast<const float2*>(my + 2 * k);
                tv[2 * k] = a.x; tv[2 * k + 1] = a.y;
            }
        }

        int ij = cell % 49;
        float gy = (float)(ij / 7);
        float gx = (float)(ij % 7);

        float iou[2];
        #pragma unroll
        for (int b = 0; b < 2; ++b) {
            const float* pb = pv + b * 5;
            const float* tb = tv + b * 5;
            float x1 = fminf(fmaxf((pb[0] + gx) * STEPV - pb[2] * 0.5f, 0.f), 1.f);
            float y1 = fminf(fmaxf((pb[1] + gy) * STEPV - pb[3] * 0.5f, 0.f), 1.f);
            float w1 = fminf(fmaxf(pb[2], 0.f), 1.f);
            float h1 = fminf(fmaxf(pb[3], 0.f), 1.f);
            float x2 = fminf(fmaxf((tb[0] + gx) * STEPV - tb[2] * 0.5f, 0.f), 1.f);
            float y2 = fminf(fmaxf((tb[1] + gy) * STEPV - tb[3] * 0.5f, 0.f), 1.f);
            float w2 = fminf(fmaxf(tb[2], 0.f), 1.f);
            float h2 = fminf(fmaxf(tb[3], 0.f), 1.f);
            float iw = fmaxf(w1 + w2 - (fmaxf(x1 + w1, x2 + w2) - fminf(x1, x2)), 0.f);
            float ih = fmaxf(h1 + h2 - (fmaxf(y1 + h1, y2 + h2) - fminf(y1, y2)), 0.f);
            float inter = iw * ih;
            float uni = w1 * h1 + w2 * h2 - inter + EPSV;
            iou[b] = inter / uni;
        }
        int best = (iou[1] > iou[0]) ? 1 : 0;   // argmax tie -> index 0

        bool sig = false;
        float obj_l = 0.f, noobj_l = 0.f, xy_l = 0.f, wh_l = 0.f;
        #pragma unroll
        for (int b = 0; b < 2; ++b) {
            const float* pb = pv + b * 5;
            const float* tb = tv + b * 5;
            bool obj0 = tb[4] > 0.f;
            sig = sig || obj0;
            bool obj = obj0 && (b == best);
            float dc = pb[4] - tb[4];
            dc *= dc;
            if (obj) {
                obj_l += dc;
                float dx = pb[0] - tb[0];
                float dy = pb[1] - tb[1];
                xy_l += dx * dx + dy * dy;
                float sw = sqrtf(tb[2] + EPSV) - sqrtf(fmaxf(pb[2], 0.f) + EPSV);
                float sh = sqrtf(tb[3] + EPSV) - sqrtf(fmaxf(pb[3], 0.f) + EPSV);
                wh_l += sw * sw + sh * sh;
            } else {
                noobj_l += dc;
            }
        }

        float cls_l = 0.f;
        if (sig) {
            #pragma unroll
            for (int c = 0; c < 20; ++c) {
                float d = pv[10 + c] - tv[10 + c];
                cls_l += d * d;
            }
        }

        loss = obj_l + L_NOOBJ * noobj_l + L_COORD * (xy_l + wh_l) + cls_l;
    }

    // ---- reduction: wave shuffle -> LDS -> one atomic per block
    #pragma unroll
    for (int off = 32; off > 0; off >>= 1)
        loss += __shfl_down(loss, off, 64);

    __shared__ float wsum[4];
    int lane = tid & 63;
    int wid  = tid >> 6;
    if (lane == 0) wsum[wid] = loss;
    __syncthreads();
    if (tid == 0) {
        float s = wsum[0] + wsum[1] + wsum[2] + wsum[3];
        atomicAdd(acc, (double)s);
    }
}

__global__ void yolo_finalize(const double* __restrict__ acc,
                              float* __restrict__ out, float invN)
{
    if (threadIdx.x == 0) out[0] = (float)(acc[0] * (double)invN);
}

extern "C" void kernel_launch(void* const* d_in, const int* in_sizes, int n_in,
                              void* d_out, int out_size, void* d_ws, size_t ws_size,
                              hipStream_t stream)
{
    const float* pred = (const float*)d_in[0];
    const float* tgt  = (const float*)d_in[1];
    float* out  = (float*)d_out;
    double* acc = (double*)d_ws;

    int ncells = in_sizes[0] / FLOATS_PER_CELL;   // N * S * S = 802816
    int N = ncells / 49;

    hipMemsetAsync(acc, 0, sizeof(double), stream);

    int blocks = (ncells + TILE - 1) / TILE;      // 3136, exact
    yolo_loss_kernel<<<blocks, 256, 0, stream>>>(pred, tgt, acc, ncells);
    yolo_finalize<<<1, 64, 0, stream>>>(acc, out, 1.0f / (float)N);
}

// Round 4
// 47.385 us; speedup vs baseline: 1.4080x; 1.4080x over previous
//
#include <hip/hip_runtime.h>

#define STEPV (1.0f / 7.0f)
#define L_COORD 5.0f
#define L_NOOBJ 0.5f
#define EPSV 1e-6f
#define FLOATS_PER_CELL 30

// 802816 cells / 256 = 3136 blocks
#define NBLOCKS 3136

__global__ __launch_bounds__(256) void yolo_loss_kernel(
    const float* __restrict__ pred,
    const float* __restrict__ tgt,
    float* __restrict__ partials,
    int ncells)
{
    int cell = blockIdx.x * blockDim.x + threadIdx.x;
    float loss = 0.0f;

    if (cell < ncells) {
        const float* p = pred + (size_t)cell * FLOATS_PER_CELL;
        const float* t = tgt  + (size_t)cell * FLOATS_PER_CELL;
        float pv[FLOATS_PER_CELL], tv[FLOATS_PER_CELL];
        #pragma unroll
        for (int k = 0; k < 15; ++k) {
            float2 a = *reinterpret_cast<const float2*>(p + 2 * k);
            pv[2 * k] = a.x; pv[2 * k + 1] = a.y;
            float2 b = *reinterpret_cast<const float2*>(t + 2 * k);
            tv[2 * k] = b.x; tv[2 * k + 1] = b.y;
        }

        int ij = cell % 49;
        float gy = (float)(ij / 7);
        float gx = (float)(ij % 7);

        float iou[2];
        #pragma unroll
        for (int b = 0; b < 2; ++b) {
            const float* pb = pv + b * 5;
            const float* tb = tv + b * 5;
            float x1 = fminf(fmaxf((pb[0] + gx) * STEPV - pb[2] * 0.5f, 0.f), 1.f);
            float y1 = fminf(fmaxf((pb[1] + gy) * STEPV - pb[3] * 0.5f, 0.f), 1.f);
            float w1 = fminf(fmaxf(pb[2], 0.f), 1.f);
            float h1 = fminf(fmaxf(pb[3], 0.f), 1.f);
            float x2 = fminf(fmaxf((tb[0] + gx) * STEPV - tb[2] * 0.5f, 0.f), 1.f);
            float y2 = fminf(fmaxf((tb[1] + gy) * STEPV - tb[3] * 0.5f, 0.f), 1.f);
            float w2 = fminf(fmaxf(tb[2], 0.f), 1.f);
            float h2 = fminf(fmaxf(tb[3], 0.f), 1.f);
            float iw = fmaxf(w1 + w2 - (fmaxf(x1 + w1, x2 + w2) - fminf(x1, x2)), 0.f);
            float ih = fmaxf(h1 + h2 - (fmaxf(y1 + h1, y2 + h2) - fminf(y1, y2)), 0.f);
            float inter = iw * ih;
            float uni = w1 * h1 + w2 * h2 - inter + EPSV;
            iou[b] = inter / uni;
        }
        int best = (iou[1] > iou[0]) ? 1 : 0;   // argmax tie -> index 0

        bool sig = false;
        float obj_l = 0.f, noobj_l = 0.f, xy_l = 0.f, wh_l = 0.f;
        #pragma unroll
        for (int b = 0; b < 2; ++b) {
            const float* pb = pv + b * 5;
            const float* tb = tv + b * 5;
            bool obj0 = tb[4] > 0.f;
            sig = sig || obj0;
            bool obj = obj0 && (b == best);
            float dc = pb[4] - tb[4];
            dc *= dc;
            if (obj) {
                obj_l += dc;
                float dx = pb[0] - tb[0];
                float dy = pb[1] - tb[1];
                xy_l += dx * dx + dy * dy;
                float sw = sqrtf(tb[2] + EPSV) - sqrtf(fmaxf(pb[2], 0.f) + EPSV);
                float sh = sqrtf(tb[3] + EPSV) - sqrtf(fmaxf(pb[3], 0.f) + EPSV);
                wh_l += sw * sw + sh * sh;
            } else {
                noobj_l += dc;
            }
        }

        float cls_l = 0.f;
        if (sig) {
            #pragma unroll
            for (int c = 0; c < 20; ++c) {
                float d = pv[10 + c] - tv[10 + c];
                cls_l += d * d;
            }
        }

        loss = obj_l + L_NOOBJ * noobj_l + L_COORD * (xy_l + wh_l) + cls_l;
    }

    // wave shuffle reduce -> LDS -> one plain store per block (NO atomic)
    #pragma unroll
    for (int off = 32; off > 0; off >>= 1)
        loss += __shfl_down(loss, off, 64);

    __shared__ float wsum[4];
    int lane = threadIdx.x & 63;
    int wid  = threadIdx.x >> 6;
    if (lane == 0) wsum[wid] = loss;
    __syncthreads();
    if (threadIdx.x == 0)
        partials[blockIdx.x] = wsum[0] + wsum[1] + wsum[2] + wsum[3];
}

__global__ __launch_bounds__(256) void yolo_finalize(
    const float* __restrict__ partials,
    float* __restrict__ out, int nparts, float invN)
{
    double s = 0.0;
    for (int i = threadIdx.x; i < nparts; i += 256)
        s += (double)partials[i];

    #pragma unroll
    for (int off = 32; off > 0; off >>= 1)
        s += __shfl_down(s, off, 64);

    __shared__ double wsum[4];
    int lane = threadIdx.x & 63;
    int wid  = threadIdx.x >> 6;
    if (lane == 0) wsum[wid] = s;
    __syncthreads();
    if (threadIdx.x == 0)
        out[0] = (float)((wsum[0] + wsum[1] + wsum[2] + wsum[3]) * (double)invN);
}

extern "C" void kernel_launch(void* const* d_in, const int* in_sizes, int n_in,
                              void* d_out, int out_size, void* d_ws, size_t ws_size,
                              hipStream_t stream)
{
    const float* pred = (const float*)d_in[0];
    const float* tgt  = (const float*)d_in[1];
    float* out      = (float*)d_out;
    float* partials = (float*)d_ws;   // NBLOCKS floats, all written each call

    int ncells = in_sizes[0] / FLOATS_PER_CELL;   // N * S * S = 802816
    int N = ncells / 49;
    int blocks = (ncells + 255) / 256;            // 3136

    yolo_loss_kernel<<<blocks, 256, 0, stream>>>(pred, tgt, partials, ncells);
    yolo_finalize<<<1, 256, 0, stream>>>(partials, out, blocks, 1.0f / (float)N);
}

// Round 5
// 38.658 us; speedup vs baseline: 1.7259x; 1.2257x over previous
//
#include <hip/hip_runtime.h>

#define STEPV (1.0f / 7.0f)
#define L_COORD 5.0f
#define L_NOOBJ 0.5f
#define EPSV 1e-6f

#define TILE 256            // cells per block
#define FLOATS_PER_CELL 30
#define TILE_FLOATS (TILE * FLOATS_PER_CELL)   // 7680 floats = 30720 B
#define TILE_F4 (TILE_FLOATS / 4)              // 1920 float4 (not divisible by 256)
#define STAGE_ITERS ((TILE_F4 + 255) / 256)    // 8 (last is half-masked)

__global__ __launch_bounds__(256) void yolo_loss_kernel(
    const float* __restrict__ pred,
    const float* __restrict__ tgt,
    float* __restrict__ partials,
    int ncells)
{
    __shared__ float buf[TILE_FLOATS];

    const int tid = threadIdx.x;
    const int cell = blockIdx.x * TILE + tid;
    const int base_f4 = blockIdx.x * TILE_F4;   // grid is exact vs total f4 count

    // ---- Phase A: stage pred tile (coalesced float4), copy own cell to regs
    {
        const float4* src = reinterpret_cast<const float4*>(pred);
        float4* dst = reinterpret_cast<float4*>(buf);
        #pragma unroll
        for (int i = 0; i < STAGE_ITERS; ++i) {
            int li = tid + i * 256;
            if (li < TILE_F4) dst[li] = src[base_f4 + li];
        }
    }
    __syncthreads();

    float pv[FLOATS_PER_CELL];
    {
        const float* my = buf + tid * FLOATS_PER_CELL;
        #pragma unroll
        for (int k = 0; k < 15; ++k) {
            float2 a = *reinterpret_cast<const float2*>(my + 2 * k);
            pv[2 * k] = a.x; pv[2 * k + 1] = a.y;
        }
    }
    __syncthreads();   // all reads of pred done before overwrite

    // ---- Phase B: stage target tile into the same buffer
    {
        const float4* src = reinterpret_cast<const float4*>(tgt);
        float4* dst = reinterpret_cast<float4*>(buf);
        #pragma unroll
        for (int i = 0; i < STAGE_ITERS; ++i) {
            int li = tid + i * 256;
            if (li < TILE_F4) dst[li] = src[base_f4 + li];
        }
    }
    __syncthreads();

    float loss = 0.0f;
    if (cell < ncells) {
        float tv[FLOATS_PER_CELL];
        {
            const float* my = buf + tid * FLOATS_PER_CELL;
            #pragma unroll
            for (int k = 0; k < 15; ++k) {
                float2 a = *reinterpret_cast<const float2*>(my + 2 * k);
                tv[2 * k] = a.x; tv[2 * k + 1] = a.y;
            }
        }

        int ij = cell % 49;
        float gy = (float)(ij / 7);
        float gx = (float)(ij % 7);

        float iou[2];
        #pragma unroll
        for (int b = 0; b < 2; ++b) {
            const float* pb = pv + b * 5;
            const float* tb = tv + b * 5;
            float x1 = fminf(fmaxf((pb[0] + gx) * STEPV - pb[2] * 0.5f, 0.f), 1.f);
            float y1 = fminf(fmaxf((pb[1] + gy) * STEPV - pb[3] * 0.5f, 0.f), 1.f);
            float w1 = fminf(fmaxf(pb[2], 0.f), 1.f);
            float h1 = fminf(fmaxf(pb[3], 0.f), 1.f);
            float x2 = fminf(fmaxf((tb[0] + gx) * STEPV - tb[2] * 0.5f, 0.f), 1.f);
            float y2 = fminf(fmaxf((tb[1] + gy) * STEPV - tb[3] * 0.5f, 0.f), 1.f);
            float w2 = fminf(fmaxf(tb[2], 0.f), 1.f);
            float h2 = fminf(fmaxf(tb[3], 0.f), 1.f);
            float iw = fmaxf(w1 + w2 - (fmaxf(x1 + w1, x2 + w2) - fminf(x1, x2)), 0.f);
            float ih = fmaxf(h1 + h2 - (fmaxf(y1 + h1, y2 + h2) - fminf(y1, y2)), 0.f);
            float inter = iw * ih;
            float uni = w1 * h1 + w2 * h2 - inter + EPSV;
            iou[b] = inter / uni;
        }
        int best = (iou[1] > iou[0]) ? 1 : 0;   // argmax tie -> index 0

        bool sig = false;
        float obj_l = 0.f, noobj_l = 0.f, xy_l = 0.f, wh_l = 0.f;
        #pragma unroll
        for (int b = 0; b < 2; ++b) {
            const float* pb = pv + b * 5;
            const float* tb = tv + b * 5;
            bool obj0 = tb[4] > 0.f;
            sig = sig || obj0;
            bool obj = obj0 && (b == best);
            float dc = pb[4] - tb[4];
            dc *= dc;
            if (obj) {
                obj_l += dc;
                float dx = pb[0] - tb[0];
                float dy = pb[1] - tb[1];
                xy_l += dx * dx + dy * dy;
                float sw = sqrtf(tb[2] + EPSV) - sqrtf(fmaxf(pb[2], 0.f) + EPSV);
                float sh = sqrtf(tb[3] + EPSV) - sqrtf(fmaxf(pb[3], 0.f) + EPSV);
                wh_l += sw * sw + sh * sh;
            } else {
                noobj_l += dc;
            }
        }

        float cls_l = 0.f;
        if (sig) {
            #pragma unroll
            for (int c = 0; c < 20; ++c) {
                float d = pv[10 + c] - tv[10 + c];
                cls_l += d * d;
            }
        }

        loss = obj_l + L_NOOBJ * noobj_l + L_COORD * (xy_l + wh_l) + cls_l;
    }

    // ---- wave shuffle reduce -> LDS -> one plain store per block (NO atomic)
    #pragma unroll
    for (int off = 32; off > 0; off >>= 1)
        loss += __shfl_down(loss, off, 64);

    __shared__ float wsum[4];
    int lane = tid & 63;
    int wid  = tid >> 6;
    if (lane == 0) wsum[wid] = loss;
    __syncthreads();
    if (tid == 0)
        partials[blockIdx.x] = wsum[0] + wsum[1] + wsum[2] + wsum[3];
}

__global__ __launch_bounds__(256) void yolo_finalize(
    const float* __restrict__ partials,
    float* __restrict__ out, int nparts, float invN)
{
    double s = 0.0;
    for (int i = threadIdx.x; i < nparts; i += 256)
        s += (double)partials[i];

    #pragma unroll
    for (int off = 32; off > 0; off >>= 1)
        s += __shfl_down(s, off, 64);

    __shared__ double wsum[4];
    int lane = threadIdx.x & 63;
    int wid  = threadIdx.x >> 6;
    if (lane == 0) wsum[wid] = s;
    __syncthreads();
    if (threadIdx.x == 0)
        out[0] = (float)((wsum[0] + wsum[1] + wsum[2] + wsum[3]) * (double)invN);
}

extern "C" void kernel_launch(void* const* d_in, const int* in_sizes, int n_in,
                              void* d_out, int out_size, void* d_ws, size_t ws_size,
                              hipStream_t stream)
{
    const float* pred = (const float*)d_in[0];
    const float* tgt  = (const float*)d_in[1];
    float* out      = (float*)d_out;
    float* partials = (float*)d_ws;   // one float per block, all written each call

    int ncells = in_sizes[0] / FLOATS_PER_CELL;   // N * S * S = 802816
    int N = ncells / 49;
    int blocks = (ncells + TILE - 1) / TILE;      // 3136, exact

    yolo_loss_kernel<<<blocks, 256, 0, stream>>>(pred, tgt, partials, ncells);
    yolo_finalize<<<1, 256, 0, stream>>>(partials, out, blocks, 1.0f / (float)N);
}